// Round 3
// baseline (1176.420 us; speedup 1.0000x reference)
//
#include <hip/hip_runtime.h>
#include <math.h>

#define BATCH 32768
#define ISZ   256
#define HSZ   512
#define KC    768   // cell GEMM K = ISZ + HSZ

typedef __attribute__((ext_vector_type(8))) short bf16x8;
typedef __attribute__((ext_vector_type(4))) float f32x4;

// bf16 activation / weight buffers (static to avoid ws_size dependence)
static __device__ unsigned short g_xbf[(size_t)BATCH * ISZ];   // x in bf16
static __device__ unsigned short g_ha [(size_t)BATCH * HSZ];   // h0 -> later h2 (bf16)
static __device__ unsigned short g_hb [(size_t)BATCH * HSZ];   // h1 -> later htmp (bf16)
static __device__ unsigned short g_ub [(size_t)BATCH * HSZ];   // tanh(W1 h + b1) (bf16)
static __device__ float          g_h2f[(size_t)BATCH * HSZ];   // new_h fp32 (RK additive path)
static __device__ unsigned short g_Wc [2048 * KC];             // [Wih | Whh] bf16 [2048][768]
static __device__ unsigned short g_W1b[HSZ * HSZ];
static __device__ unsigned short g_W2b[HSZ * HSZ];

__device__ __forceinline__ unsigned short f2bf(float f) {
    unsigned int u = __float_as_uint(f);
    u += 0x7fff + ((u >> 16) & 1);   // RNE
    return (unsigned short)(u >> 16);
}
__device__ __forceinline__ float fsigm(float x) { return 1.0f / (1.0f + __expf(-x)); }
__device__ __forceinline__ float ftanh(float x) { return 1.0f - 2.0f / (__expf(2.0f * x) + 1.0f); }

__device__ __forceinline__ void gload16(const void* g, void* l) {
    __builtin_amdgcn_global_load_lds(
        (const __attribute__((address_space(1))) unsigned int*)g,
        (__attribute__((address_space(3))) unsigned int*)l, 16, 0, 0);
}

// ---------------------------------------------------------------------------
// fp32 -> bf16 conversion (float4-vectorized, row restride for Wih|Whh concat)
// ---------------------------------------------------------------------------
template <int DST>
__global__ __launch_bounds__(256) void conv_kernel(
    const float* __restrict__ src, int nv, int w4shift, int dstride, int doff)
{
    unsigned short* __restrict__ dst =
        DST == 0 ? g_xbf : DST == 1 ? g_ha : DST == 2 ? g_Wc : DST == 3 ? g_W1b : g_W2b;
    int i = blockIdx.x * 256 + threadIdx.x;
    const int gs = gridDim.x * 256;
    for (; i < nv; i += gs) {
        const int r = i >> w4shift;
        const int c = i & ((1 << w4shift) - 1);
        const float4 v = ((const float4*)src)[i];
        ushort4 o;
        o.x = f2bf(v.x); o.y = f2bf(v.y); o.z = f2bf(v.z); o.w = f2bf(v.w);
        *(ushort4*)&dst[(size_t)r * dstride + doff + c * 4] = o;
    }
}

// ---------------------------------------------------------------------------
// Unified MFMA GEMM. Block = 128 rows x 2 n-tiles of 128 vcols (shared A
// staging), 4 waves, per wave 4x4 frags per n-tile. BK=64, 2-phase loop.
// Grid is 1D with bijective XCD swizzle, n-chunk fastest within an XCD so the
// A-panel is fetched once per XCD and re-served from its L2.
// MODE 0: cell1  z=[x|h0(g_ha)]@Wc^T -> h1->g_hb,          c: c0->out_c
// MODE 1: cell2  z=[x|h1(g_hb)]@Wc^T -> h2->g_ha + g_h2f,  c: out_c->out_c
// MODE 2: u = tanh(g_ha @ W1^T + b1) -> g_ub
// MODE 3: u = tanh(g_hb @ W1^T + b1) -> g_ub
// MODE 11..14: k = g_ub @ W2^T + b2 ; RK accumulate in accht, htmp -> g_hb
// ---------------------------------------------------------------------------
template <int MODE>
__global__ __launch_bounds__(256) void gemm_kernel(
    const float* __restrict__ p0, const float* __restrict__ p1,
    const float* __restrict__ p2, float* __restrict__ p3,
    const float* __restrict__ ts, float* __restrict__ accht)
{
    constexpr bool CELL = (MODE <= 1);
    constexpr int KTOT = CELL ? KC : HSZ;
    constexpr int NKT  = KTOT / 64;
    constexpr int NCH  = CELL ? 8 : 2;   // n-chunks in grid (256 vcols each)

    __shared__ __align__(16) unsigned short As[128 * 64];
    __shared__ __align__(16) unsigned short Bs[2 * 128 * 64];

    // bijective XCD swizzle (nwg divisible by 8), n-chunk fastest per XCD
    const int orig = blockIdx.x;
    const int q = gridDim.x >> 3;
    const int wg = (orig & 7) * q + (orig >> 3);
    const int nbc = wg % NCH;
    const int mBase = (wg / NCH) * 128;

    const int tid  = threadIdx.x;
    const int lane = tid & 63;
    const int wid  = tid >> 6;
    const int wr   = wid >> 1, wc = wid & 1;
    const int l15  = lane & 15, lq = lane >> 4;

    const unsigned short* __restrict__ Ah;
    const unsigned short* __restrict__ Bsrc;
    if constexpr (MODE == 0)      { Ah = g_ha; Bsrc = g_Wc;  }
    else if constexpr (MODE == 1) { Ah = g_hb; Bsrc = g_Wc;  }
    else if constexpr (MODE == 2) { Ah = g_ha; Bsrc = g_W1b; }
    else if constexpr (MODE == 3) { Ah = g_hb; Bsrc = g_W1b; }
    else                          { Ah = g_ub; Bsrc = g_W2b; }

    // staging mapping: slot s = j*256 + tid; row = s>>3, 16B-chunk = s&7
    const int arow = tid >> 3, ch = tid & 7;
    int bgrow[2][4];
#pragma unroll
    for (int nt = 0; nt < 2; ++nt)
#pragma unroll
        for (int j = 0; j < 4; ++j) {
            const int vr = j * 32 + arow;
            if constexpr (CELL) {
                const int g    = (vr >> 4) & 3;
                const int jcol = nbc * 64 + nt * 32 + (vr >> 6) * 16 + (vr & 15);
                bgrow[nt][j] = g * 512 + jcol;
            } else {
                bgrow[nt][j] = nbc * 256 + nt * 128 + vr;
            }
        }

    f32x4 acc[2][4][4];
#pragma unroll
    for (int nt = 0; nt < 2; ++nt)
#pragma unroll
        for (int fm = 0; fm < 4; ++fm)
#pragma unroll
            for (int fn = 0; fn < 4; ++fn) acc[nt][fm][fn] = (f32x4){0.f, 0.f, 0.f, 0.f};

    for (int kt = 0; kt < NKT; ++kt) {
        const int k0 = kt * 64;
#pragma unroll
        for (int j = 0; j < 4; ++j) {
            const int row = j * 32 + arow;
            const unsigned short* ga;
            if constexpr (CELL) {
                ga = (k0 < 256)
                   ? g_xbf + (size_t)(mBase + row) * ISZ + (k0       + ch * 8)
                   : Ah    + (size_t)(mBase + row) * HSZ + (k0 - 256 + ch * 8);
            } else {
                ga = Ah + (size_t)(mBase + row) * HSZ + k0 + ch * 8;
            }
            gload16(ga, (char*)As + j * 4096 + wid * 1024);
#pragma unroll
            for (int nt = 0; nt < 2; ++nt) {
                const unsigned short* gb = Bsrc + (size_t)bgrow[nt][j] * KTOT + k0 + ch * 8;
                gload16(gb, (char*)Bs + nt * 16384 + j * 4096 + wid * 1024);
            }
        }
        __syncthreads();
#pragma unroll
        for (int kk = 0; kk < 2; ++kk) {
            bf16x8 a[4], b[2][4];
#pragma unroll
            for (int f = 0; f < 4; ++f) {
                const int rowA = wr * 64 + f * 16 + l15;
                a[f] = *(const bf16x8*)((const char*)As + rowA * 128 + kk * 64 + lq * 16);
#pragma unroll
                for (int nt = 0; nt < 2; ++nt) {
                    const int rowB = wc * 64 + f * 16 + l15;
                    b[nt][f] = *(const bf16x8*)((const char*)Bs + nt * 16384 + rowB * 128 + kk * 64 + lq * 16);
                }
            }
#pragma unroll
            for (int nt = 0; nt < 2; ++nt)
#pragma unroll
                for (int fm = 0; fm < 4; ++fm)
#pragma unroll
                    for (int fn = 0; fn < 4; ++fn)
                        acc[nt][fm][fn] = __builtin_amdgcn_mfma_f32_16x16x32_bf16(
                            a[fm], b[nt][fn], acc[nt][fm][fn], 0, 0, 0);
        }
        __syncthreads();
    }

    // ---------------- epilogue ----------------
    if constexpr (CELL) {
        const float* __restrict__ bih = p0;
        const float* __restrict__ bhh = p1;
        const float* __restrict__ c_in = p2;
        float* __restrict__ c_out = p3;
#pragma unroll
        for (int nt = 0; nt < 2; ++nt) {
            const int j = nbc * 64 + nt * 32 + wc * 16 + l15;
            float bsum[4];
#pragma unroll
            for (int g = 0; g < 4; ++g) bsum[g] = bih[g * 512 + j] + bhh[g * 512 + j];
#pragma unroll
            for (int fm = 0; fm < 4; ++fm) {
#pragma unroll
                for (int r = 0; r < 4; ++r) {
                    const int m = mBase + wr * 64 + fm * 16 + lq * 4 + r;
                    const size_t idx = (size_t)m * HSZ + j;
                    const float ig = fsigm(acc[nt][fm][0][r] + bsum[0]);
                    const float fg = fsigm(acc[nt][fm][1][r] + bsum[1]);
                    const float gg = ftanh(acc[nt][fm][2][r] + bsum[2]);
                    const float og = fsigm(acc[nt][fm][3][r] + bsum[3]);
                    const float cnew = fg * c_in[idx] + ig * gg;
                    const float hnew = og * ftanh(cnew);
                    c_out[idx] = cnew;
                    if constexpr (MODE == 0) {
                        g_hb[idx] = f2bf(hnew);
                    } else {
                        g_ha[idx] = f2bf(hnew);
                        g_h2f[idx] = hnew;
                    }
                }
            }
        }
    } else if constexpr (MODE == 2 || MODE == 3) {
        const float* __restrict__ b1 = p0;
#pragma unroll
        for (int nt = 0; nt < 2; ++nt)
#pragma unroll
            for (int fm = 0; fm < 4; ++fm)
#pragma unroll
                for (int r = 0; r < 4; ++r) {
                    const int m = mBase + wr * 64 + fm * 16 + lq * 4 + r;
#pragma unroll
                    for (int fn = 0; fn < 4; ++fn) {
                        const int n = nbc * 256 + nt * 128 + wc * 64 + fn * 16 + l15;
                        g_ub[(size_t)m * HSZ + n] = f2bf(ftanh(acc[nt][fm][fn][r] + b1[n]));
                    }
                }
    } else {
        const float* __restrict__ b2 = p0;
#pragma unroll
        for (int nt = 0; nt < 2; ++nt)
#pragma unroll
            for (int fm = 0; fm < 4; ++fm)
#pragma unroll
                for (int r = 0; r < 4; ++r) {
                    const int m = mBase + wr * 64 + fm * 16 + lq * 4 + r;
                    const float dtv = ts[2 * m + 1] - ts[2 * m];
#pragma unroll
                    for (int fn = 0; fn < 4; ++fn) {
                        const int n = nbc * 256 + nt * 128 + wc * 64 + fn * 16 + l15;
                        const size_t idx = (size_t)m * HSZ + n;
                        const float kv = acc[nt][fm][fn][r] + b2[n];
                        if constexpr (MODE == 11) {
                            accht[idx] = kv;
                            g_hb[idx] = f2bf(g_h2f[idx] + 0.5f * dtv * kv);
                        } else if constexpr (MODE == 12) {
                            accht[idx] += 2.0f * kv;
                            g_hb[idx] = f2bf(g_h2f[idx] + 0.5f * dtv * kv);
                        } else if constexpr (MODE == 13) {
                            accht[idx] += 2.0f * kv;
                            g_hb[idx] = f2bf(g_h2f[idx] + dtv * kv);
                        } else {
                            accht[idx] = g_h2f[idx] + dtv * (1.0f / 6.0f) * (accht[idx] + kv);
                        }
                    }
                }
    }
}

extern "C" void kernel_launch(void* const* d_in, const int* in_sizes, int n_in,
                              void* d_out, int out_size, void* d_ws, size_t ws_size,
                              hipStream_t stream) {
    const float* x   = (const float*)d_in[0];
    const float* h0  = (const float*)d_in[1];
    const float* c0  = (const float*)d_in[2];
    const float* ts  = (const float*)d_in[3];
    const float* Wih = (const float*)d_in[4];
    const float* Whh = (const float*)d_in[5];
    const float* bih = (const float*)d_in[6];
    const float* bhh = (const float*)d_in[7];
    const float* W1  = (const float*)d_in[8];
    const float* b1  = (const float*)d_in[9];
    const float* W2  = (const float*)d_in[10];
    const float* b2  = (const float*)d_in[11];

    float* out_ht = (float*)d_out;
    float* out_c  = out_ht + (size_t)BATCH * HSZ;

    dim3 blk(256);
    conv_kernel<0><<<2048, blk, 0, stream>>>(x,   BATCH * ISZ / 4, 6, ISZ, 0);
    conv_kernel<1><<<2048, blk, 0, stream>>>(h0,  BATCH * HSZ / 4, 7, HSZ, 0);
    conv_kernel<2><<<256,  blk, 0, stream>>>(Wih, 2048 * 256 / 4,  6, KC, 0);
    conv_kernel<2><<<256,  blk, 0, stream>>>(Whh, 2048 * 512 / 4,  7, KC, 256);
    conv_kernel<3><<<256,  blk, 0, stream>>>(W1,  HSZ * HSZ / 4,   7, HSZ, 0);
    conv_kernel<4><<<256,  blk, 0, stream>>>(W2,  HSZ * HSZ / 4,   7, HSZ, 0);

    dim3 gcell(BATCH / 128 * 8);   // 2048 blocks: 8 n-chunks x 256 m-panels
    dim3 gode(BATCH / 128 * 2);    // 512 blocks:  2 n-chunks x 256 m-panels

    gemm_kernel<0><<<gcell, blk, 0, stream>>>(bih, bhh, c0,    out_c, nullptr, nullptr);
    gemm_kernel<1><<<gcell, blk, 0, stream>>>(bih, bhh, out_c, out_c, nullptr, nullptr);

    gemm_kernel<2 ><<<gode, blk, 0, stream>>>(b1, nullptr, nullptr, nullptr, ts, out_ht);
    gemm_kernel<11><<<gode, blk, 0, stream>>>(b2, nullptr, nullptr, nullptr, ts, out_ht);
    gemm_kernel<3 ><<<gode, blk, 0, stream>>>(b1, nullptr, nullptr, nullptr, ts, out_ht);
    gemm_kernel<12><<<gode, blk, 0, stream>>>(b2, nullptr, nullptr, nullptr, ts, out_ht);
    gemm_kernel<3 ><<<gode, blk, 0, stream>>>(b1, nullptr, nullptr, nullptr, ts, out_ht);
    gemm_kernel<13><<<gode, blk, 0, stream>>>(b2, nullptr, nullptr, nullptr, ts, out_ht);
    gemm_kernel<3 ><<<gode, blk, 0, stream>>>(b1, nullptr, nullptr, nullptr, ts, out_ht);
    gemm_kernel<14><<<gode, blk, 0, stream>>>(b2, nullptr, nullptr, nullptr, ts, out_ht);
}

// Round 4
// 1040.415 us; speedup vs baseline: 1.1307x; 1.1307x over previous
//
#include <hip/hip_runtime.h>
#include <math.h>

#define BATCH 32768
#define ISZ   256
#define HSZ   512
#define KC    768   // cell GEMM K = ISZ + HSZ

typedef __attribute__((ext_vector_type(8))) short bf16x8;
typedef __attribute__((ext_vector_type(4))) float f32x4;

// bf16 activation / weight buffers (static to avoid ws_size dependence)
static __device__ unsigned short g_xbf[(size_t)BATCH * ISZ];   // x in bf16
static __device__ unsigned short g_ha [(size_t)BATCH * HSZ];   // h0 -> later h2 (bf16)
static __device__ unsigned short g_hb [(size_t)BATCH * HSZ];   // h1 -> later htmp (bf16)
static __device__ unsigned short g_ub [(size_t)BATCH * HSZ];   // tanh(W1 h + b1) (bf16)
static __device__ float          g_h2f[(size_t)BATCH * HSZ];   // new_h fp32 (RK additive path)
static __device__ unsigned short g_Wc [2048 * KC];             // [Wih | Whh] bf16 [2048][768]
static __device__ unsigned short g_W1b[HSZ * HSZ];
static __device__ unsigned short g_W2b[HSZ * HSZ];

__device__ __forceinline__ unsigned short f2bf(float f) {
    unsigned int u = __float_as_uint(f);
    u += 0x7fff + ((u >> 16) & 1);   // RNE
    return (unsigned short)(u >> 16);
}
__device__ __forceinline__ float fsigm(float x) { return 1.0f / (1.0f + __expf(-x)); }
__device__ __forceinline__ float ftanh(float x) { return 1.0f - 2.0f / (__expf(2.0f * x) + 1.0f); }

__device__ __forceinline__ void gload16(const void* g, void* l) {
    __builtin_amdgcn_global_load_lds(
        (const __attribute__((address_space(1))) unsigned int*)g,
        (__attribute__((address_space(3))) unsigned int*)l, 16, 0, 0);
}

// ---------------------------------------------------------------------------
// fp32 -> bf16 conversion (float4-vectorized, row restride for Wih|Whh concat)
// ---------------------------------------------------------------------------
template <int DST>
__global__ __launch_bounds__(256) void conv_kernel(
    const float* __restrict__ src, int nv, int w4shift, int dstride, int doff)
{
    unsigned short* __restrict__ dst =
        DST == 0 ? g_xbf : DST == 1 ? g_ha : DST == 2 ? g_Wc : DST == 3 ? g_W1b : g_W2b;
    int i = blockIdx.x * 256 + threadIdx.x;
    const int gs = gridDim.x * 256;
    for (; i < nv; i += gs) {
        const int r = i >> w4shift;
        const int c = i & ((1 << w4shift) - 1);
        const float4 v = ((const float4*)src)[i];
        ushort4 o;
        o.x = f2bf(v.x); o.y = f2bf(v.y); o.z = f2bf(v.z); o.w = f2bf(v.w);
        *(ushort4*)&dst[(size_t)r * dstride + doff + c * 4] = o;
    }
}

// ---------------------------------------------------------------------------
// Unified MFMA GEMM, 128x128 tile, BK=64, 4 waves, 4x4 frags/wave.
// T3-min double-buffered K-loop: stage(next) -> vmcnt(8) (counted; next-tile
// loads stay in flight) -> s_barrier -> 32 MFMA -> s_barrier.
// 1D grid, bijective XCD swizzle, n-chunk fastest within an XCD (A-panel L2
// reuse).
// MODE 0: cell1  z=[x|h0(g_ha)]@Wc^T -> h1->g_hb,          c: c0->out_c
// MODE 1: cell2  z=[x|h1(g_hb)]@Wc^T -> h2->g_ha + g_h2f,  c: out_c->out_c
// MODE 2: u = tanh(g_ha @ W1^T + b1) -> g_ub
// MODE 3: u = tanh(g_hb @ W1^T + b1) -> g_ub
// MODE 11..14: k = g_ub @ W2^T + b2 ; RK accumulate in accht, htmp -> g_hb
// ---------------------------------------------------------------------------
template <int MODE>
__global__ __launch_bounds__(256) void gemm_kernel(
    const float* __restrict__ p0, const float* __restrict__ p1,
    const float* __restrict__ p2, float* __restrict__ p3,
    const float* __restrict__ ts, float* __restrict__ accht)
{
    constexpr bool CELL = (MODE <= 1);
    constexpr int KTOT = CELL ? KC : HSZ;
    constexpr int NKT  = KTOT / 64;
    constexpr int NCH  = CELL ? 16 : 4;   // n-chunks (128 vcols each)

    __shared__ __align__(16) unsigned short As[2][128 * 64];
    __shared__ __align__(16) unsigned short Bs[2][128 * 64];

    // bijective XCD swizzle (nwg divisible by 8), n-chunk fastest per XCD
    const int orig = blockIdx.x;
    const int q = gridDim.x >> 3;
    const int wg = (orig & 7) * q + (orig >> 3);
    const int nbc = wg % NCH;
    const int mBase = (wg / NCH) * 128;

    const int tid  = threadIdx.x;
    const int lane = tid & 63;
    const int wid  = tid >> 6;
    const int wr   = wid >> 1, wc = wid & 1;
    const int l15  = lane & 15, lq = lane >> 4;

    const unsigned short* __restrict__ Ah;
    const unsigned short* __restrict__ Bsrc;
    if constexpr (MODE == 0)      { Ah = g_ha; Bsrc = g_Wc;  }
    else if constexpr (MODE == 1) { Ah = g_hb; Bsrc = g_Wc;  }
    else if constexpr (MODE == 2) { Ah = g_ha; Bsrc = g_W1b; }
    else if constexpr (MODE == 3) { Ah = g_hb; Bsrc = g_W1b; }
    else                          { Ah = g_ub; Bsrc = g_W2b; }

    // staging mapping: slot s = j*256 + tid; row = s>>3, 16B-chunk = s&7
    const int arow = tid >> 3, ch = tid & 7;
    int bgrow[4];
#pragma unroll
    for (int j = 0; j < 4; ++j) {
        const int vr = j * 32 + arow;
        if constexpr (CELL) {
            const int g    = (vr >> 4) & 3;
            const int jcol = nbc * 32 + (vr >> 6) * 16 + (vr & 15);
            bgrow[j] = g * 512 + jcol;
        } else {
            bgrow[j] = nbc * 128 + vr;
        }
    }

    auto stage = [&](int buf, int kt) {
        const int k0 = kt * 64;
#pragma unroll
        for (int j = 0; j < 4; ++j) {
            const int row = j * 32 + arow;
            const unsigned short* ga;
            if constexpr (CELL) {
                ga = (k0 < 256)
                   ? g_xbf + (size_t)(mBase + row) * ISZ + (k0       + ch * 8)
                   : Ah    + (size_t)(mBase + row) * HSZ + (k0 - 256 + ch * 8);
            } else {
                ga = Ah + (size_t)(mBase + row) * HSZ + k0 + ch * 8;
            }
            gload16(ga, (char*)As[buf] + j * 4096 + wid * 1024);
            const unsigned short* gb = Bsrc + (size_t)bgrow[j] * KTOT + k0 + ch * 8;
            gload16(gb, (char*)Bs[buf] + j * 4096 + wid * 1024);
        }
    };

    f32x4 acc[4][4];
#pragma unroll
    for (int fm = 0; fm < 4; ++fm)
#pragma unroll
        for (int fn = 0; fn < 4; ++fn) acc[fm][fn] = (f32x4){0.f, 0.f, 0.f, 0.f};

    stage(0, 0);
    int cur = 0;
    for (int kt = 0; kt < NKT; ++kt) {
        if (kt + 1 < NKT) {
            stage(cur ^ 1, kt + 1);
            asm volatile("s_waitcnt vmcnt(8)" ::: "memory");
        } else {
            asm volatile("s_waitcnt vmcnt(0)" ::: "memory");
        }
        asm volatile("s_barrier" ::: "memory");
#pragma unroll
        for (int kk = 0; kk < 2; ++kk) {
            bf16x8 a[4], b[4];
#pragma unroll
            for (int f = 0; f < 4; ++f) {
                const int rowA = wr * 64 + f * 16 + l15;
                a[f] = *(const bf16x8*)((const char*)As[cur] + rowA * 128 + kk * 64 + lq * 16);
                const int rowB = wc * 64 + f * 16 + l15;
                b[f] = *(const bf16x8*)((const char*)Bs[cur] + rowB * 128 + kk * 64 + lq * 16);
            }
#pragma unroll
            for (int fm = 0; fm < 4; ++fm)
#pragma unroll
                for (int fn = 0; fn < 4; ++fn)
                    acc[fm][fn] = __builtin_amdgcn_mfma_f32_16x16x32_bf16(
                        a[fm], b[fn], acc[fm][fn], 0, 0, 0);
        }
        asm volatile("s_barrier" ::: "memory");
        cur ^= 1;
    }

    // ---------------- epilogue ----------------
    if constexpr (CELL) {
        const float* __restrict__ bih = p0;
        const float* __restrict__ bhh = p1;
        const float* __restrict__ c_in = p2;
        float* __restrict__ c_out = p3;
        const int j = nbc * 32 + wc * 16 + l15;
        float bsum[4];
#pragma unroll
        for (int g = 0; g < 4; ++g) bsum[g] = bih[g * 512 + j] + bhh[g * 512 + j];
#pragma unroll
        for (int fm = 0; fm < 4; ++fm) {
#pragma unroll
            for (int r = 0; r < 4; ++r) {
                const int m = mBase + wr * 64 + fm * 16 + lq * 4 + r;
                const size_t idx = (size_t)m * HSZ + j;
                const float ig = fsigm(acc[fm][0][r] + bsum[0]);
                const float fg = fsigm(acc[fm][1][r] + bsum[1]);
                const float gg = ftanh(acc[fm][2][r] + bsum[2]);
                const float og = fsigm(acc[fm][3][r] + bsum[3]);
                const float cnew = fg * c_in[idx] + ig * gg;
                const float hnew = og * ftanh(cnew);
                c_out[idx] = cnew;
                if constexpr (MODE == 0) {
                    g_hb[idx] = f2bf(hnew);
                } else {
                    g_ha[idx] = f2bf(hnew);
                    g_h2f[idx] = hnew;
                }
            }
        }
    } else if constexpr (MODE == 2 || MODE == 3) {
        const float* __restrict__ b1 = p0;
#pragma unroll
        for (int fm = 0; fm < 4; ++fm)
#pragma unroll
            for (int r = 0; r < 4; ++r) {
                const int m = mBase + wr * 64 + fm * 16 + lq * 4 + r;
#pragma unroll
                for (int fn = 0; fn < 4; ++fn) {
                    const int n = nbc * 128 + wc * 64 + fn * 16 + l15;
                    g_ub[(size_t)m * HSZ + n] = f2bf(ftanh(acc[fm][fn][r] + b1[n]));
                }
            }
    } else {
        const float* __restrict__ b2 = p0;
#pragma unroll
        for (int fm = 0; fm < 4; ++fm)
#pragma unroll
            for (int r = 0; r < 4; ++r) {
                const int m = mBase + wr * 64 + fm * 16 + lq * 4 + r;
                const float dtv = ts[2 * m + 1] - ts[2 * m];
#pragma unroll
                for (int fn = 0; fn < 4; ++fn) {
                    const int n = nbc * 128 + wc * 64 + fn * 16 + l15;
                    const size_t idx = (size_t)m * HSZ + n;
                    const float kv = acc[fm][fn][r] + b2[n];
                    if constexpr (MODE == 11) {
                        accht[idx] = kv;
                        g_hb[idx] = f2bf(g_h2f[idx] + 0.5f * dtv * kv);
                    } else if constexpr (MODE == 12) {
                        accht[idx] += 2.0f * kv;
                        g_hb[idx] = f2bf(g_h2f[idx] + 0.5f * dtv * kv);
                    } else if constexpr (MODE == 13) {
                        accht[idx] += 2.0f * kv;
                        g_hb[idx] = f2bf(g_h2f[idx] + dtv * kv);
                    } else {
                        accht[idx] = g_h2f[idx] + dtv * (1.0f / 6.0f) * (accht[idx] + kv);
                    }
                }
            }
    }
}

extern "C" void kernel_launch(void* const* d_in, const int* in_sizes, int n_in,
                              void* d_out, int out_size, void* d_ws, size_t ws_size,
                              hipStream_t stream) {
    const float* x   = (const float*)d_in[0];
    const float* h0  = (const float*)d_in[1];
    const float* c0  = (const float*)d_in[2];
    const float* ts  = (const float*)d_in[3];
    const float* Wih = (const float*)d_in[4];
    const float* Whh = (const float*)d_in[5];
    const float* bih = (const float*)d_in[6];
    const float* bhh = (const float*)d_in[7];
    const float* W1  = (const float*)d_in[8];
    const float* b1  = (const float*)d_in[9];
    const float* W2  = (const float*)d_in[10];
    const float* b2  = (const float*)d_in[11];

    float* out_ht = (float*)d_out;
    float* out_c  = out_ht + (size_t)BATCH * HSZ;

    dim3 blk(256);
    conv_kernel<0><<<2048, blk, 0, stream>>>(x,   BATCH * ISZ / 4, 6, ISZ, 0);
    conv_kernel<1><<<2048, blk, 0, stream>>>(h0,  BATCH * HSZ / 4, 7, HSZ, 0);
    conv_kernel<2><<<256,  blk, 0, stream>>>(Wih, 2048 * 256 / 4,  6, KC, 0);
    conv_kernel<2><<<256,  blk, 0, stream>>>(Whh, 2048 * 512 / 4,  7, KC, 256);
    conv_kernel<3><<<256,  blk, 0, stream>>>(W1,  HSZ * HSZ / 4,   7, HSZ, 0);
    conv_kernel<4><<<256,  blk, 0, stream>>>(W2,  HSZ * HSZ / 4,   7, HSZ, 0);

    dim3 gcell(BATCH / 128 * 16);  // 4096 blocks: 16 n-chunks x 256 m-panels
    dim3 gode(BATCH / 128 * 4);    // 1024 blocks:  4 n-chunks x 256 m-panels

    gemm_kernel<0><<<gcell, blk, 0, stream>>>(bih, bhh, c0,    out_c, nullptr, nullptr);
    gemm_kernel<1><<<gcell, blk, 0, stream>>>(bih, bhh, out_c, out_c, nullptr, nullptr);

    gemm_kernel<2 ><<<gode, blk, 0, stream>>>(b1, nullptr, nullptr, nullptr, ts, out_ht);
    gemm_kernel<11><<<gode, blk, 0, stream>>>(b2, nullptr, nullptr, nullptr, ts, out_ht);
    gemm_kernel<3 ><<<gode, blk, 0, stream>>>(b1, nullptr, nullptr, nullptr, ts, out_ht);
    gemm_kernel<12><<<gode, blk, 0, stream>>>(b2, nullptr, nullptr, nullptr, ts, out_ht);
    gemm_kernel<3 ><<<gode, blk, 0, stream>>>(b1, nullptr, nullptr, nullptr, ts, out_ht);
    gemm_kernel<13><<<gode, blk, 0, stream>>>(b2, nullptr, nullptr, nullptr, ts, out_ht);
    gemm_kernel<3 ><<<gode, blk, 0, stream>>>(b1, nullptr, nullptr, nullptr, ts, out_ht);
    gemm_kernel<14><<<gode, blk, 0, stream>>>(b2, nullptr, nullptr, nullptr, ts, out_ht);
}